// Round 13
// baseline (747.060 us; speedup 1.0000x reference)
//
#include <hip/hip_runtime.h>
#include <stdint.h>

typedef unsigned short u16;
typedef __attribute__((ext_vector_type(8))) short s16x8;
typedef __attribute__((ext_vector_type(8))) unsigned short u16x8;
typedef __attribute__((ext_vector_type(4))) float f32x4;

#define N_TOK 8192
#define DDIM 2048
#define HDIM 2048
#define NROWS 16384
#define PADROWS 17408
#define MAXTILES 136
#define KTILES 64

// ---- ws layout (bytes) ----
#define W1T_OFF    0ull
#define W3T_OFF    67108864ull
#define W2T_OFF    134217728ull
#define XBF_OFF    201326592ull
#define HS_OFF     234881024ull              // 16640 x 2048 bf16
#define ROWTOK_OFF 303038464ull              // 17408 ints
#define POS_OFF    303108096ull              // 16384 ints
#define META_OFF   303173632ull
#define RES_OFF    0ull                      // overlays w1T/w3T (dead after gemm1)
#define WS_NEED    303173760ull

__device__ __forceinline__ u16 f2bf(float f) {
  union { float f; unsigned u; } v; v.f = f;
  unsigned r = v.u + 0x7fffu + ((v.u >> 16) & 1u);
  return (u16)(r >> 16);
}
__device__ __forceinline__ float bf2f(u16 u) {
  union { unsigned u; float f; } v; v.u = ((unsigned)u) << 16; return v.f;
}
__device__ __forceinline__ void gload_lds16(const u16* g, u16* l) {
  __builtin_amdgcn_global_load_lds(
      (const __attribute__((address_space(1))) unsigned int*)g,
      (__attribute__((address_space(3))) unsigned int*)l, 16, 0, 0);
}

// ---------------- routing (128-row tiles) ----------------
__global__ void r1_kernel(const int* __restrict__ bsz, int* __restrict__ meta,
                          int* __restrict__ rowtok) {
  if (threadIdx.x == 0) {
    int off = 0, tbv = 0;
    meta[8] = 0; meta[17] = 0;
    for (int e = 0; e < 8; ++e) {
      meta[e] = 0;
      int c = bsz[e];
      off += c;  meta[9 + e] = off;
      tbv += (c + 127) >> 7; meta[18 + e] = tbv;
    }
  }
  for (int p = NROWS + (int)threadIdx.x; p < PADROWS; p += 256) rowtok[p] = 0;
}

__global__ void r2_kernel(const int* __restrict__ eidx, int* __restrict__ meta,
                          int* __restrict__ rowtok, int* __restrict__ posOf) {
  int i = blockIdx.x * 256 + threadIdx.x;
  int e = eidx[i];
  int p = atomicAdd(&meta[e], 1);
  int row = meta[8 + e] + p;
  rowtok[row] = i >> 1;
  posOf[i] = row;
}

// ---------------- converts ----------------
__global__ void convert_x_kernel(const float* __restrict__ x, u16* __restrict__ xbf) {
  long long c = blockIdx.x * 256 + threadIdx.x;
  const float4 v0 = *(const float4*)&x[c * 8];
  const float4 v1 = *(const float4*)&x[c * 8 + 4];
  u16x8 u;
  u[0] = f2bf(v0.x); u[1] = f2bf(v0.y); u[2] = f2bf(v0.z); u[3] = f2bf(v0.w);
  u[4] = f2bf(v1.x); u[5] = f2bf(v1.y); u[6] = f2bf(v1.z); u[7] = f2bf(v1.w);
  *(u16x8*)&xbf[c * 8] = u;
}

__global__ __launch_bounds__(256) void transpose_cvt_kernel(
    const float* __restrict__ w1, const float* __restrict__ w2, const float* __restrict__ w3,
    u16* __restrict__ w1T, u16* __restrict__ w2T, u16* __restrict__ w3T) {
  __shared__ float tile[64][65];
  int z = blockIdx.z;
  const float* src; u16* dst;
  if (z < 8)        { src = w1 + (size_t)z * 4194304;        dst = w1T + (size_t)z * 4194304; }
  else if (z < 16)  { src = w3 + (size_t)(z - 8) * 4194304;  dst = w3T + (size_t)(z - 8) * 4194304; }
  else              { src = w2 + (size_t)(z - 16) * 4194304; dst = w2T + (size_t)(z - 16) * 4194304; }
  int r0 = blockIdx.y * 64, c0 = blockIdx.x * 64;
  int tid = threadIdx.x;
  int lr = tid >> 4, lc4 = (tid & 15) * 4;
#pragma unroll
  for (int i = 0; i < 4; ++i) {
    const float4 v = *(const float4*)&src[(size_t)(r0 + lr + i * 16) * 2048 + c0 + lc4];
    tile[lr + i * 16][lc4 + 0] = v.x; tile[lr + i * 16][lc4 + 1] = v.y;
    tile[lr + i * 16][lc4 + 2] = v.z; tile[lr + i * 16][lc4 + 3] = v.w;
  }
  __syncthreads();
  int orb = tid >> 3, oc8 = (tid & 7) * 8;
#pragma unroll
  for (int i = 0; i < 2; ++i) {
    int orow = orb + i * 32;
    u16x8 u;
#pragma unroll
    for (int j = 0; j < 8; ++j) u[j] = f2bf(tile[oc8 + j][orow]);
    *(u16x8*)&dst[(size_t)(c0 + orow) * 2048 + r0 + oc8] = u;
  }
}

// ---------------- grouped dual-B GEMM: fine 2-phase stagger + 4 blocks/CU ----------------
// 256 thr / 4 waves (2x2), tile 128 rows x (64+64) cols, BK=32, ring-2 LDS 32 KiB.
// Per tile: ph0 {read A(4)+B1(2); stage A'; vmcnt(2)+lgkm(4); BAR; lgkm0; 8 MFMA acc1; BAR}
//           ph1 {read B3(2); stage B1',B3'; vmcnt(1); BAR; lgkm0; 8 MFMA acc3; BAR}
// LEDGER (stationary, issue order A,A,B1,B3 per tile):
//   ph0 entry outstanding = B3(t); +A'(2) -> vmcnt(2) retires B3(t)   [read ph1]
//   ph1: +B1',B3' -> 4 outstanding -> vmcnt(1) retires A'(2),B1'      [read t+1 ph0]
//   B3' certified at t+1 ph0's vmcnt(2). Never drains in main loop.
// 4 blocks/CU (32 KiB LDS, <=128 VGPR): cross-block wave overlap absorbs the
// barrier/wait windows (m114) that pinned every 1-block variant at ~38%.
template<int EPI>
__device__ __forceinline__ void gemm_body(
    const u16* __restrict__ A, const u16* __restrict__ B1m, const u16* __restrict__ B3m,
    const int* __restrict__ gather, const int* __restrict__ meta, u16* __restrict__ out) {
  const int* offs = meta + 8;
  const int* tb = meta + 17;

  // XCD super-block walk: 8 tileIds x 4 colbs per super-block
  const int NCOLB = EPI ? 32 : 16;
  const int CG = NCOLB / 4;
  const int nper = (MAXTILES * NCOLB) / 8;
  const int lin = (int)blockIdx.x;
  const int w = (lin & 7) * nper + (lin >> 3);
  const int sb = w >> 5, t5 = w & 31;
  const int tileId = (sb / CG) * 8 + (t5 >> 2);
  const int colb = (sb % CG) * 4 + (t5 & 3);

  if (tileId >= tb[8]) return;
  int e = 0;
#pragma unroll
  for (int qq = 1; qq < 8; ++qq) if (tileId >= tb[qq]) e = qq;
  const int row0 = offs[e] + (tileId - tb[e]) * 128;
  const int vr = offs[e + 1] - row0;

  const int bRowA = EPI ? colb * 64 : colb * 128;
  const int bRowB = EPI ? colb * 64 : colb * 128 + 64;

  // flat per-buf layout (u16): A @0 (128x32=4096), B1 @4096 (64x32), B3 @6144
  __shared__ u16 lds[2][8192];   // 32 KiB ring

  const int tid = threadIdx.x;
  const int wid = tid >> 6, lane = tid & 63;
  const int lm = lane & 15, kg = lane >> 4;
  const int wr = wid >> 1, wc = wid & 1;   // 2x2 wave grid

  // ---- stage pointers; source chunk-permuted to match swizzled read
  // slot s holds row r=s>>2, chunk c=(s&3)^((r>>1)&3) (16B chunks, 4/row)
  const u16* pA[2]; const u16* pB1; const u16* pB3;
  int dA[2], dB1, dB3;
#pragma unroll
  for (int l = 0; l < 2; ++l) {
    int S = (wid + l * 4) * 64 + lane;      // 0..511
    int r = S >> 2;
    int c8 = ((S & 3) ^ ((r >> 1) & 3)) * 8;
    int ga = row0 + r;
    int ta = gather ? gather[ga] : ga;
    pA[l] = A + (size_t)ta * 2048 + c8;
    dA[l] = (wid + l * 4) * 512;
  }
  {
    int S = wid * 64 + lane;                // 0..255
    int r = S >> 2;
    int c8 = ((S & 3) ^ ((r >> 1) & 3)) * 8;
    pB1 = B1m + ((size_t)e * 2048 + bRowA + r) * 2048 + c8;
    pB3 = B3m + ((size_t)e * 2048 + bRowB + r) * 2048 + c8;
    dB1 = 4096 + wid * 512;
    dB3 = 6144 + wid * 512;
  }

  // read offsets: k-chunk kg swizzled by ((row>>1)&3) = ((lm)>>1)&3
  const int fK = (kg ^ ((lm >> 1) & 3)) * 8;
  const int aBase  = (wr * 64 + lm) * 32 + fK;
  const int b1Base = 4096 + (wc * 32 + lm) * 32 + fK;

  f32x4 acc1[4][2], acc3[4][2];
  f32x4 z4 = {0.f, 0.f, 0.f, 0.f};
#pragma unroll
  for (int m = 0; m < 4; ++m)
#pragma unroll
    for (int n = 0; n < 2; ++n) { acc1[m][n] = z4; acc3[m][n] = z4; }

  s16x8 a[4], b1[2], b3[2];

#define STG_A(bf) do { \
    gload_lds16(pA[0], &lds[bf][dA[0]]); \
    gload_lds16(pA[1], &lds[bf][dA[1]]); \
    pA[0] += 32; pA[1] += 32; } while (0)
#define STG_B(bf) do { \
    gload_lds16(pB1, &lds[bf][dB1]); \
    gload_lds16(pB3, &lds[bf][dB3]); \
    pB1 += 32; pB3 += 32; } while (0)
#define READ_A4(cur) do { \
_Pragma("unroll") \
    for (int mi = 0; mi < 4; ++mi) \
      a[mi] = *(const s16x8*)&lds[cur][aBase + mi * 512]; } while (0)
#define READ_B1(cur) do { \
_Pragma("unroll") \
    for (int n = 0; n < 2; ++n) \
      b1[n] = *(const s16x8*)&lds[cur][b1Base + n * 512]; } while (0)
#define READ_B3(cur) do { \
_Pragma("unroll") \
    for (int n = 0; n < 2; ++n) \
      b3[n] = *(const s16x8*)&lds[cur][b1Base + 2048 + n * 512]; } while (0)
#define MFMA8(ACC, B) do { \
    __builtin_amdgcn_s_setprio(1); \
_Pragma("unroll") \
    for (int mi = 0; mi < 4; ++mi) \
_Pragma("unroll") \
      for (int n = 0; n < 2; ++n) \
        ACC[mi][n] = __builtin_amdgcn_mfma_f32_16x16x32_bf16(a[mi], B[n], ACC[mi][n], 0, 0, 0); \
    __builtin_amdgcn_s_setprio(0); } while (0)
#define ABAR() asm volatile("s_barrier" ::: "memory")
#define LGKM0_FENCE() do { asm volatile("s_waitcnt lgkmcnt(0)" ::: "memory"); \
    __builtin_amdgcn_sched_barrier(0); } while (0)

#define TILE_MAIN(cur) do { \
    /* ph0: A,B1 certified by prev ph1's vmcnt(1)+ABAR */ \
    READ_A4(cur); READ_B1(cur); \
    STG_A(cur ^ 1); \
    asm volatile("s_waitcnt vmcnt(2) lgkmcnt(4)" ::: "memory"); \
    ABAR(); LGKM0_FENCE(); \
    MFMA8(acc1, b1); \
    ABAR(); \
    /* ph1: B3 certified by ph0's vmcnt(2)+ABAR */ \
    READ_B3(cur); \
    STG_B(cur ^ 1); \
    asm volatile("s_waitcnt vmcnt(1)" ::: "memory"); \
    ABAR(); LGKM0_FENCE(); \
    MFMA8(acc3, b3); \
    ABAR(); } while (0)

#define TILE_LAST(cur) do { \
    READ_A4(cur); READ_B1(cur); \
    asm volatile("s_waitcnt vmcnt(0) lgkmcnt(4)" ::: "memory"); \
    ABAR(); LGKM0_FENCE(); \
    MFMA8(acc1, b1); \
    ABAR(); \
    READ_B3(cur); \
    LGKM0_FENCE(); \
    MFMA8(acc3, b3); } while (0)

  // prologue: issue A,A,B1,B3 of tile 0; certify A,A,B1 (B3 left in flight)
  STG_A(0);
  STG_B(0);
  asm volatile("s_waitcnt vmcnt(1)" ::: "memory");
  ABAR();

  for (int t = 0; t < KTILES - 2; t += 2) {
    TILE_MAIN(0);
    TILE_MAIN(1);
  }
  TILE_MAIN(0);   // t=62, stages tile 63 into buf 1
  TILE_LAST(1);   // t=63

  // ---- epilogue
#pragma unroll
  for (int m = 0; m < 4; ++m)
#pragma unroll
    for (int n = 0; n < 2; ++n) {
      const int rloc = wr * 64 + m * 16 + kg * 4;
      if (EPI == 1) {
        const int col = colb * 64 + wc * 32 + n * 16 + lm;
#pragma unroll
        for (int rr = 0; rr < 4; ++rr) {
          int rowl = rloc + rr;
          if (rowl < vr) {
            float z = acc1[m][n][rr];
            float h = z / (1.f + __expf(-z)) * acc3[m][n][rr];
            out[(size_t)(row0 + rowl) * 2048 + col] = f2bf(h);
          }
        }
      } else {
        const int col = colb * 128 + wc * 32 + n * 16 + lm;
#pragma unroll
        for (int rr = 0; rr < 4; ++rr) {
          int rowl = rloc + rr;
          if (rowl < vr) {
            out[(size_t)(row0 + rowl) * 2048 + col] = f2bf(acc1[m][n][rr]);
            out[(size_t)(row0 + rowl) * 2048 + col + 64] = f2bf(acc3[m][n][rr]);
          }
        }
      }
    }
#undef STG_A
#undef STG_B
#undef READ_A4
#undef READ_B1
#undef READ_B3
#undef MFMA8
#undef ABAR
#undef LGKM0_FENCE
#undef TILE_MAIN
#undef TILE_LAST
}

__global__ __launch_bounds__(256, 4) void gemm1_kernel(
    const u16* __restrict__ A, const u16* __restrict__ B1m, const u16* __restrict__ B3m,
    const int* __restrict__ gather, const int* __restrict__ meta, u16* __restrict__ out) {
  gemm_body<1>(A, B1m, B3m, gather, meta, out);
}
__global__ __launch_bounds__(256, 4) void gemm2_kernel(
    const u16* __restrict__ A, const u16* __restrict__ B1m, const u16* __restrict__ B3m,
    const int* __restrict__ gather, const int* __restrict__ meta, u16* __restrict__ out) {
  gemm_body<0>(A, B1m, B3m, gather, meta, out);
}

// ---------------- combine ----------------
__global__ void combine_kernel(const u16* __restrict__ res, const int* __restrict__ posOf,
                               const float* __restrict__ ew, float* __restrict__ out) {
  int c = blockIdx.x * 256 + threadIdx.x;
  int t = c >> 8, dc = (c & 255) * 8;
  int p0 = posOf[2 * t], p1 = posOf[2 * t + 1];
  float wa = ew[2 * t], wb = ew[2 * t + 1];
  u16x8 u0 = *(const u16x8*)&res[(size_t)p0 * 2048 + dc];
  u16x8 u1 = *(const u16x8*)&res[(size_t)p1 * 2048 + dc];
  float4 o0, o1;
  o0.x = wa * bf2f(u0[0]) + wb * bf2f(u1[0]);
  o0.y = wa * bf2f(u0[1]) + wb * bf2f(u1[1]);
  o0.z = wa * bf2f(u0[2]) + wb * bf2f(u1[2]);
  o0.w = wa * bf2f(u0[3]) + wb * bf2f(u1[3]);
  o1.x = wa * bf2f(u0[4]) + wb * bf2f(u1[4]);
  o1.y = wa * bf2f(u0[5]) + wb * bf2f(u1[5]);
  o1.z = wa * bf2f(u0[6]) + wb * bf2f(u1[6]);
  o1.w = wa * bf2f(u0[7]) + wb * bf2f(u1[7]);
  *(float4*)&out[(size_t)t * 2048 + dc] = o0;
  *(float4*)&out[(size_t)t * 2048 + dc + 4] = o1;
}

extern "C" void kernel_launch(void* const* d_in, const int* in_sizes, int n_in,
                              void* d_out, int out_size, void* d_ws, size_t ws_size,
                              hipStream_t stream) {
  const float* x  = (const float*)d_in[0];
  const float* ew = (const float*)d_in[1];
  const int* eidx = (const int*)d_in[2];
  const int* bsz  = (const int*)d_in[3];
  const float* w1 = (const float*)d_in[4];
  const float* w2 = (const float*)d_in[5];
  const float* w3 = (const float*)d_in[6];
  float* out = (float*)d_out;
  char* ws = (char*)d_ws;

  if (ws_size < WS_NEED) {
    hipMemsetAsync(d_out, 0, (size_t)out_size * 4, stream);
    return;
  }

  u16* w1T = (u16*)(ws + W1T_OFF);
  u16* w3T = (u16*)(ws + W3T_OFF);
  u16* w2T = (u16*)(ws + W2T_OFF);
  u16* xbf = (u16*)(ws + XBF_OFF);
  u16* hs  = (u16*)(ws + HS_OFF);
  u16* res = (u16*)(ws + RES_OFF);   // overlays w1T/w3T (dead after gemm1)
  int* rowtok = (int*)(ws + ROWTOK_OFF);
  int* posOf  = (int*)(ws + POS_OFF);
  int* meta   = (int*)(ws + META_OFF);

  r1_kernel<<<1, 256, 0, stream>>>(bsz, meta, rowtok);
  r2_kernel<<<64, 256, 0, stream>>>(eidx, meta, rowtok, posOf);
  convert_x_kernel<<<8192, 256, 0, stream>>>(x, xbf);
  transpose_cvt_kernel<<<dim3(32, 32, 24), 256, 0, stream>>>(w1, w2, w3, w1T, w2T, w3T);
  gemm1_kernel<<<MAXTILES * 32, 256, 0, stream>>>(xbf, w1T, w3T, rowtok, meta, hs);
  gemm2_kernel<<<MAXTILES * 16, 256, 0, stream>>>(hs, w2T, w2T, nullptr, meta, res);
  combine_kernel<<<8192, 256, 0, stream>>>(res, posOf, ew, out);
}

// Round 14
// 692.133 us; speedup vs baseline: 1.0794x; 1.0794x over previous
//
#include <hip/hip_runtime.h>
#include <stdint.h>

typedef unsigned short u16;
typedef __attribute__((ext_vector_type(8))) short s16x8;
typedef __attribute__((ext_vector_type(8))) unsigned short u16x8;
typedef __attribute__((ext_vector_type(4))) float f32x4;

#define N_TOK 8192
#define DDIM 2048
#define HDIM 2048
#define NROWS 16384
#define PADROWS 16640
#define MAXTILES 72
#define KTILES 32

// ---- ws layout (bytes) ----
#define W1T_OFF    0ull
#define W3T_OFF    67108864ull
#define W2T_OFF    134217728ull
#define XBF_OFF    201326592ull
#define HS_OFF     234881024ull              // 16640 x 2048 bf16
#define ROWTOK_OFF 303038464ull
#define POS_OFF    303107072ull
#define META_OFF   303172608ull
#define RES_OFF    0ull                      // overlays w1T/w3T (dead after gemm1)
#define WS_NEED    303172736ull

__device__ __forceinline__ u16 f2bf(float f) {
  union { float f; unsigned u; } v; v.f = f;
  unsigned r = v.u + 0x7fffu + ((v.u >> 16) & 1u);
  return (u16)(r >> 16);
}
__device__ __forceinline__ float bf2f(u16 u) {
  union { unsigned u; float f; } v; v.u = ((unsigned)u) << 16; return v.f;
}
__device__ __forceinline__ void gload_lds16(const u16* g, u16* l) {
  __builtin_amdgcn_global_load_lds(
      (const __attribute__((address_space(1))) unsigned int*)g,
      (__attribute__((address_space(3))) unsigned int*)l, 16, 0, 0);
}

// ---------------- routing (256-row tiles) ----------------
__global__ void r1_kernel(const int* __restrict__ bsz, int* __restrict__ meta,
                          int* __restrict__ rowtok) {
  if (threadIdx.x == 0) {
    int off = 0, tbv = 0;
    meta[8] = 0; meta[17] = 0;
    for (int e = 0; e < 8; ++e) {
      meta[e] = 0;
      int c = bsz[e];
      off += c;  meta[9 + e] = off;
      tbv += (c + 255) >> 8; meta[18 + e] = tbv;
    }
  }
  for (int p = NROWS + (int)threadIdx.x; p < PADROWS; p += 256) rowtok[p] = 0;
}

__global__ void r2_kernel(const int* __restrict__ eidx, int* __restrict__ meta,
                          int* __restrict__ rowtok, int* __restrict__ posOf) {
  int i = blockIdx.x * 256 + threadIdx.x;
  int e = eidx[i];
  int p = atomicAdd(&meta[e], 1);
  int row = meta[8 + e] + p;
  rowtok[row] = i >> 1;
  posOf[i] = row;
}

// ---------------- converts ----------------
__global__ void convert_x_kernel(const float* __restrict__ x, u16* __restrict__ xbf) {
  long long c = blockIdx.x * 256 + threadIdx.x;
  const float4 v0 = *(const float4*)&x[c * 8];
  const float4 v1 = *(const float4*)&x[c * 8 + 4];
  u16x8 u;
  u[0] = f2bf(v0.x); u[1] = f2bf(v0.y); u[2] = f2bf(v0.z); u[3] = f2bf(v0.w);
  u[4] = f2bf(v1.x); u[5] = f2bf(v1.y); u[6] = f2bf(v1.z); u[7] = f2bf(v1.w);
  *(u16x8*)&xbf[c * 8] = u;
}

__global__ __launch_bounds__(256) void transpose_cvt_kernel(
    const float* __restrict__ w1, const float* __restrict__ w2, const float* __restrict__ w3,
    u16* __restrict__ w1T, u16* __restrict__ w2T, u16* __restrict__ w3T) {
  __shared__ float tile[64][65];
  int z = blockIdx.z;
  const float* src; u16* dst;
  if (z < 8)        { src = w1 + (size_t)z * 4194304;        dst = w1T + (size_t)z * 4194304; }
  else if (z < 16)  { src = w3 + (size_t)(z - 8) * 4194304;  dst = w3T + (size_t)(z - 8) * 4194304; }
  else              { src = w2 + (size_t)(z - 16) * 4194304; dst = w2T + (size_t)(z - 16) * 4194304; }
  int r0 = blockIdx.y * 64, c0 = blockIdx.x * 64;
  int tid = threadIdx.x;
  int lr = tid >> 4, lc4 = (tid & 15) * 4;
#pragma unroll
  for (int i = 0; i < 4; ++i) {
    const float4 v = *(const float4*)&src[(size_t)(r0 + lr + i * 16) * 2048 + c0 + lc4];
    tile[lr + i * 16][lc4 + 0] = v.x; tile[lr + i * 16][lc4 + 1] = v.y;
    tile[lr + i * 16][lc4 + 2] = v.z; tile[lr + i * 16][lc4 + 3] = v.w;
  }
  __syncthreads();
  int orb = tid >> 3, oc8 = (tid & 7) * 8;
#pragma unroll
  for (int i = 0; i < 2; ++i) {
    int orow = orb + i * 32;
    u16x8 u;
#pragma unroll
    for (int j = 0; j < 8; ++j) u[j] = f2bf(tile[oc8 + j][orow]);
    *(u16x8*)&dst[(size_t)(c0 + orow) * 2048 + r0 + oc8] = u;
  }
}

// ---------------- grouped dual-B GEMM, staggered 4-phase counted schedule ----------------
// (R12, measured best: gemm1 ~851 TF / 38.5% MfmaUtil, total 691 us)
// LEDGER:
//   ph0 reads A0,A1,B1 ; ph1 reads B3 ; ph2 reads A0,A1 (half1) ; ph3 no reads.
//   stage order: ph0 -> A0',B1' ; ph1 -> A1',B3'.
//   t ph0: in-flight B3(t)+4 = 6 -> vmcnt(4) certifies B3(t)      [read t ph1]
//   t ph3: in-flight 8          -> vmcnt(2) certifies A0',B1',A1' [read t+1 ph0]
//   B3' certified by t+1 ph0's vmcnt(4). Never drains in main loop.
// EPI=1: out[row][colb*128+c] = silu(A@B1) * (A@B3)
// EPI=0: out[row][colb*256+c] = A@B1 ; +128 = A@B3 (both = w2T sub-panels)
template<int EPI>
__device__ __forceinline__ void gemm_body(
    const u16* __restrict__ A, const u16* __restrict__ B1m, const u16* __restrict__ B3m,
    const int* __restrict__ gather, const int* __restrict__ meta, u16* __restrict__ out) {
  const int* offs = meta + 8;
  const int* tb = meta + 17;

  // XCD super-block locality mapping (8 tileIds x 4 colbs per super-block)
  const int NCOLB = EPI ? 16 : 8;
  const int CG = NCOLB / 4;
  const int nper = (MAXTILES * NCOLB) / 8;
  const int lin = (int)blockIdx.x;
  const int w = (lin & 7) * nper + (lin >> 3);
  const int sb = w >> 5, t5 = w & 31;
  const int tileId = (sb / CG) * 8 + (t5 >> 2);
  const int colb = (sb % CG) * 4 + (t5 & 3);

  if (tileId >= tb[8]) return;
  int e = 0;
#pragma unroll
  for (int qq = 1; qq < 8; ++qq) if (tileId >= tb[qq]) e = qq;
  const int row0 = offs[e] + (tileId - tb[e]) * 256;
  const int vr = offs[e + 1] - row0;

  const int bRowA = EPI ? colb * 128 : colb * 256;
  const int bRowB = EPI ? colb * 128 : colb * 256 + 128;

  __shared__ u16 lds[2][4][8192];  // [buf][A0,A1,B1,B3] = 128 KiB

  const int tid = threadIdx.x;
  const int wid = tid >> 6, lane = tid & 63;
  const int lm = lane & 15, kg = lane >> 4;
  const int wr = wid >> 2, wc = wid & 3;

  // stage pointers (2 gloads per unit per thread), chunk-permuted source
  const u16* pA0[2]; const u16* pA1[2]; const u16* pB1[2]; const u16* pB3[2];
#pragma unroll
  for (int l = 0; l < 2; ++l) {
    int S = (wid * 2 + l) * 64 + lane;
    int r = S >> 3;
    int c8 = ((S & 7) ^ (r & 7)) * 8;
    int ga0 = row0 + r, ga1 = row0 + 128 + r;
    int ta0 = gather ? gather[ga0] : ga0;
    int ta1 = gather ? gather[ga1] : ga1;
    pA0[l] = A + (size_t)ta0 * 2048 + c8;
    pA1[l] = A + (size_t)ta1 * 2048 + c8;
    pB1[l] = B1m + ((size_t)e * 2048 + bRowA + r) * 2048 + c8;
    pB3[l] = B3m + ((size_t)e * 2048 + bRowB + r) * 2048 + c8;
  }

  // frag-read offsets: elem = lm*64 + ((kk*4+kg)^(lm&7))*8
  int fA[2];
  fA[0] = lm * 64 + ((kg) ^ (lm & 7)) * 8;
  fA[1] = lm * 64 + ((4 + kg) ^ (lm & 7)) * 8;

  f32x4 acc1[8][2], acc3[8][2];
  f32x4 z4 = {0.f, 0.f, 0.f, 0.f};
#pragma unroll
  for (int m = 0; m < 8; ++m)
#pragma unroll
    for (int n = 0; n < 2; ++n) { acc1[m][n] = z4; acc3[m][n] = z4; }

  s16x8 a[4][2], b1r[2][2], b3r[2][2];

#define STG(b, u, P) do { \
    gload_lds16(P[0], &lds[b][u][(wid * 2 + 0) * 512]); \
    gload_lds16(P[1], &lds[b][u][(wid * 2 + 1) * 512]); \
    P[0] += 64; P[1] += 64; } while (0)
#define READ_A(cur, half) do { \
_Pragma("unroll") \
    for (int mi = 0; mi < 4; ++mi) \
_Pragma("unroll") \
      for (int kk = 0; kk < 2; ++kk) \
        a[mi][kk] = *(const s16x8*)&lds[cur][wr][((half) * 4 + mi) * 1024 + fA[kk]]; \
    } while (0)
#define READ_B1(cur) do { \
_Pragma("unroll") \
    for (int n = 0; n < 2; ++n) \
_Pragma("unroll") \
      for (int kk = 0; kk < 2; ++kk) \
        b1r[n][kk] = *(const s16x8*)&lds[cur][2][wc * 2048 + n * 1024 + fA[kk]]; \
    } while (0)
#define READ_B3(cur) do { \
_Pragma("unroll") \
    for (int n = 0; n < 2; ++n) \
_Pragma("unroll") \
      for (int kk = 0; kk < 2; ++kk) \
        b3r[n][kk] = *(const s16x8*)&lds[cur][3][wc * 2048 + n * 1024 + fA[kk]]; \
    } while (0)
#define MFMA16(ACC, half, B) do { \
    __builtin_amdgcn_s_setprio(1); \
_Pragma("unroll") \
    for (int mi = 0; mi < 4; ++mi) \
_Pragma("unroll") \
      for (int n = 0; n < 2; ++n) { \
        ACC[(half)*4+mi][n] = __builtin_amdgcn_mfma_f32_16x16x32_bf16(a[mi][0], B[n][0], ACC[(half)*4+mi][n], 0, 0, 0); \
        ACC[(half)*4+mi][n] = __builtin_amdgcn_mfma_f32_16x16x32_bf16(a[mi][1], B[n][1], ACC[(half)*4+mi][n], 0, 0, 0); \
      } \
    __builtin_amdgcn_s_setprio(0); } while (0)
#define ABAR() asm volatile("s_barrier" ::: "memory")
#define LGKM0_FENCE() do { asm volatile("s_waitcnt lgkmcnt(0)" ::: "memory"); \
    __builtin_amdgcn_sched_barrier(0); } while (0)

#define TILE_MAIN(cur) do { \
    /* ph0: reads certified by prev tile ph3 vmcnt(2)+ABAR */ \
    READ_A(cur, 0); READ_B1(cur); \
    STG(cur ^ 1, 0, pA0); STG(cur ^ 1, 2, pB1); \
    asm volatile("s_waitcnt vmcnt(4) lgkmcnt(8)" ::: "memory"); \
    ABAR(); LGKM0_FENCE(); \
    MFMA16(acc1, 0, b1r); \
    ABAR(); \
    /* ph1: B3(t) certified by ph0 vmcnt(4)+ABAR */ \
    READ_B3(cur); \
    STG(cur ^ 1, 1, pA1); STG(cur ^ 1, 3, pB3); \
    ABAR(); LGKM0_FENCE(); \
    MFMA16(acc3, 0, b3r); \
    ABAR(); \
    /* ph2: A half1 (units certified long ago) */ \
    READ_A(cur, 1); \
    ABAR(); LGKM0_FENCE(); \
    MFMA16(acc1, 1, b1r); \
    ABAR(); \
    /* ph3: certify next tile's A0',B1',A1' */ \
    asm volatile("s_waitcnt vmcnt(2)" ::: "memory"); \
    ABAR(); \
    MFMA16(acc3, 1, b3r); \
    ABAR(); } while (0)

#define TILE_LAST(cur) do { \
    READ_A(cur, 0); READ_B1(cur); \
    asm volatile("s_waitcnt vmcnt(0) lgkmcnt(8)" ::: "memory"); \
    ABAR(); LGKM0_FENCE(); \
    MFMA16(acc1, 0, b1r); \
    ABAR(); \
    READ_B3(cur); \
    ABAR(); LGKM0_FENCE(); \
    MFMA16(acc3, 0, b3r); \
    ABAR(); \
    READ_A(cur, 1); \
    ABAR(); LGKM0_FENCE(); \
    MFMA16(acc1, 1, b1r); \
    ABAR(); \
    MFMA16(acc3, 1, b3r); } while (0)

  // prologue: issue tile 0 in ledger order A0,B1,A1,B3; certify A0,B1,A1
  STG(0, 0, pA0);
  STG(0, 2, pB1);
  STG(0, 1, pA1);
  STG(0, 3, pB3);
  asm volatile("s_waitcnt vmcnt(2)" ::: "memory");
  ABAR();

  for (int t = 0; t < KTILES - 2; t += 2) {
    TILE_MAIN(0);
    TILE_MAIN(1);
  }
  TILE_MAIN(0);
  TILE_LAST(1);

  // ---- epilogue
#pragma unroll
  for (int m = 0; m < 8; ++m)
#pragma unroll
    for (int n = 0; n < 2; ++n) {
      const int rloc = wr * 128 + m * 16 + kg * 4;
      if (EPI == 1) {
        const int col = colb * 128 + wc * 32 + n * 16 + lm;
#pragma unroll
        for (int rr = 0; rr < 4; ++rr) {
          int rowl = rloc + rr;
          if (rowl < vr) {
            float z = acc1[m][n][rr];
            float h = z / (1.f + __expf(-z)) * acc3[m][n][rr];
            out[(size_t)(row0 + rowl) * 2048 + col] = f2bf(h);
          }
        }
      } else {
        const int col = colb * 256 + wc * 32 + n * 16 + lm;
#pragma unroll
        for (int rr = 0; rr < 4; ++rr) {
          int rowl = rloc + rr;
          if (rowl < vr) {
            out[(size_t)(row0 + rowl) * 2048 + col] = f2bf(acc1[m][n][rr]);
            out[(size_t)(row0 + rowl) * 2048 + col + 128] = f2bf(acc3[m][n][rr]);
          }
        }
      }
    }
#undef STG
#undef READ_A
#undef READ_B1
#undef READ_B3
#undef MFMA16
#undef ABAR
#undef LGKM0_FENCE
#undef TILE_MAIN
#undef TILE_LAST
}

__global__ __launch_bounds__(512, 2) void gemm1_kernel(
    const u16* __restrict__ A, const u16* __restrict__ B1m, const u16* __restrict__ B3m,
    const int* __restrict__ gather, const int* __restrict__ meta, u16* __restrict__ out) {
  gemm_body<1>(A, B1m, B3m, gather, meta, out);
}
__global__ __launch_bounds__(512, 2) void gemm2_kernel(
    const u16* __restrict__ A, const u16* __restrict__ B1m, const u16* __restrict__ B3m,
    const int* __restrict__ gather, const int* __restrict__ meta, u16* __restrict__ out) {
  gemm_body<0>(A, B1m, B3m, gather, meta, out);
}

// ---------------- combine ----------------
__global__ void combine_kernel(const u16* __restrict__ res, const int* __restrict__ posOf,
                               const float* __restrict__ ew, float* __restrict__ out) {
  int c = blockIdx.x * 256 + threadIdx.x;
  int t = c >> 8, dc = (c & 255) * 8;
  int p0 = posOf[2 * t], p1 = posOf[2 * t + 1];
  float wa = ew[2 * t], wb = ew[2 * t + 1];
  u16x8 u0 = *(const u16x8*)&res[(size_t)p0 * 2048 + dc];
  u16x8 u1 = *(const u16x8*)&res[(size_t)p1 * 2048 + dc];
  float4 o0, o1;
  o0.x = wa * bf2f(u0[0]) + wb * bf2f(u1[0]);
  o0.y = wa * bf2f(u0[1]) + wb * bf2f(u1[1]);
  o0.z = wa * bf2f(u0[2]) + wb * bf2f(u1[2]);
  o0.w = wa * bf2f(u0[3]) + wb * bf2f(u1[3]);
  o1.x = wa * bf2f(u0[4]) + wb * bf2f(u1[4]);
  o1.y = wa * bf2f(u0[5]) + wb * bf2f(u1[5]);
  o1.z = wa * bf2f(u0[6]) + wb * bf2f(u1[6]);
  o1.w = wa * bf2f(u0[7]) + wb * bf2f(u1[7]);
  *(float4*)&out[(size_t)t * 2048 + dc] = o0;
  *(float4*)&out[(size_t)t * 2048 + dc + 4] = o1;
}

extern "C" void kernel_launch(void* const* d_in, const int* in_sizes, int n_in,
                              void* d_out, int out_size, void* d_ws, size_t ws_size,
                              hipStream_t stream) {
  const float* x  = (const float*)d_in[0];
  const float* ew = (const float*)d_in[1];
  const int* eidx = (const int*)d_in[2];
  const int* bsz  = (const int*)d_in[3];
  const float* w1 = (const float*)d_in[4];
  const float* w2 = (const float*)d_in[5];
  const float* w3 = (const float*)d_in[6];
  float* out = (float*)d_out;
  char* ws = (char*)d_ws;

  if (ws_size < WS_NEED) {
    hipMemsetAsync(d_out, 0, (size_t)out_size * 4, stream);
    return;
  }

  u16* w1T = (u16*)(ws + W1T_OFF);
  u16* w3T = (u16*)(ws + W3T_OFF);
  u16* w2T = (u16*)(ws + W2T_OFF);
  u16* xbf = (u16*)(ws + XBF_OFF);
  u16* hs  = (u16*)(ws + HS_OFF);
  u16* res = (u16*)(ws + RES_OFF);   // overlays w1T/w3T (dead after gemm1)
  int* rowtok = (int*)(ws + ROWTOK_OFF);
  int* posOf  = (int*)(ws + POS_OFF);
  int* meta   = (int*)(ws + META_OFF);

  r1_kernel<<<1, 256, 0, stream>>>(bsz, meta, rowtok);
  r2_kernel<<<64, 256, 0, stream>>>(eidx, meta, rowtok, posOf);
  convert_x_kernel<<<8192, 256, 0, stream>>>(x, xbf);
  transpose_cvt_kernel<<<dim3(32, 32, 24), 256, 0, stream>>>(w1, w2, w3, w1T, w2T, w3T);
  gemm1_kernel<<<MAXTILES * 16, 512, 0, stream>>>(xbf, w1T, w3T, rowtok, meta, hs);
  gemm2_kernel<<<MAXTILES * 8, 512, 0, stream>>>(hs, w2T, w2T, nullptr, meta, res);
  combine_kernel<<<8192, 256, 0, stream>>>(res, posOf, ew, out);
}